// Round 4
// baseline (1126.258 us; speedup 1.0000x reference)
//
#include <hip/hip_runtime.h>
#include <hip/hip_bf16.h>
#include <stdint.h>

// Problem dims (fixed by the reference)
#define B_DIM   8192
#define LAT     256
#define MEM_DIM 200
#define NPIX    16384          // IMG*IMG = 128*128
#define RPB     16             // batch rows per block in row_kernel (round-1 proven)
#define CHUNK   40             // memory rows per LDS chunk (5 chunks x 40 = 200)

typedef short bf16x8 __attribute__((ext_vector_type(8)));
typedef float f32x4  __attribute__((ext_vector_type(4)));

__device__ __forceinline__ float wred_sum(float v) {
#pragma unroll
  for (int m = 32; m; m >>= 1) v += __shfl_xor(v, m, 64);
  return v;
}
__device__ __forceinline__ float wred_max(float v) {
#pragma unroll
  for (int m = 32; m; m >>= 1) v = fmaxf(v, __shfl_xor(v, m, 64));
  return v;
}
// round-to-nearest-even fp32 -> bf16 (bit trick; inputs are normal floats)
__device__ __forceinline__ unsigned short f2bf(float f) {
  unsigned u = __builtin_bit_cast(unsigned, f);
  u = u + 0x7FFFu + ((u >> 16) & 1u);
  return (unsigned short)(u >> 16);
}

// ---------------- memory row norms: mn[m] = ||memory[m,:]|| ----------------
__global__ void __launch_bounds__(64) mem_norm_kernel(const float* __restrict__ mem,
                                                      float* __restrict__ mn) {
  const int m = blockIdx.x, lane = threadIdx.x;
  float4 v = ((const float4*)(mem + (size_t)m * LAT))[lane];
  float ss = v.x * v.x + v.y * v.y + v.z * v.z + v.w * v.w;
  ss = wred_sum(ss);
  if (lane == 0) mn[m] = sqrtf(ss);
}

// ---------------- W fp32 -> bf16 (row-major [NPIX][LAT]) ----------------
__global__ void __launch_bounds__(256) convert_w_kernel(const float* __restrict__ W,
                                                        unsigned short* __restrict__ Wb) {
  const int i = blockIdx.x * 256 + threadIdx.x;   // quad index, grid covers exactly NPIX*LAT/4
  float4 v = ((const float4*)W)[i];
  ushort4 o;
  o.x = f2bf(v.x); o.y = f2bf(v.y); o.z = f2bf(v.z); o.w = f2bf(v.w);
  ((ushort4*)Wb)[i] = o;
}

// ---------------- fused per-row pipeline (round-1 version, measured-good) ----------------
__global__ void __launch_bounds__(256) row_kernel(
    const float* __restrict__ z, const float* __restrict__ mem,
    const float* __restrict__ mn_g, float* __restrict__ zhat_out,
    float* __restrict__ w_out, unsigned short* __restrict__ zhat_bf) {
  __shared__ float msh[CHUNK * LAT];     // 40 KB
  __shared__ float lw[RPB][MEM_DIM];     // 12.8 KB: raw dots, then final w
  __shared__ float mnsh[MEM_DIM];

  const int tid = threadIdx.x;
  const int lane = tid & 63;
  const int wid = tid >> 6;
  const int row0 = blockIdx.x * RPB;

  if (tid < MEM_DIM) mnsh[tid] = mn_g[tid];

  float4 zr[4];
  float zn[4];
#pragma unroll
  for (int r = 0; r < 4; ++r) {
    const int row = row0 + wid * 4 + r;
    zr[r] = *(const float4*)(z + (size_t)row * LAT + lane * 4);
    float ss = zr[r].x * zr[r].x + zr[r].y * zr[r].y + zr[r].z * zr[r].z + zr[r].w * zr[r].w;
    zn[r] = sqrtf(wred_sum(ss));
  }

  // ---- phase 1: raw dot products  lw[r][m] = z_r . mem[m] ----
  for (int c = 0; c < 5; ++c) {
    __syncthreads();
    const float4* gsrc = (const float4*)(mem + (size_t)c * CHUNK * LAT);
    float4* msh4 = (float4*)msh;
    for (int i = tid; i < CHUNK * 64; i += 256) msh4[i] = gsrc[i];
    __syncthreads();
    for (int mm = 0; mm < CHUNK; ++mm) {
      float4 mv = ((float4*)msh)[mm * 64 + lane];
      float p0 = mv.x * zr[0].x + mv.y * zr[0].y + mv.z * zr[0].z + mv.w * zr[0].w;
      float p1 = mv.x * zr[1].x + mv.y * zr[1].y + mv.z * zr[1].z + mv.w * zr[1].w;
      float p2 = mv.x * zr[2].x + mv.y * zr[2].y + mv.z * zr[2].z + mv.w * zr[2].w;
      float p3 = mv.x * zr[3].x + mv.y * zr[3].y + mv.z * zr[3].z + mv.w * zr[3].w;
      p0 = wred_sum(p0); p1 = wred_sum(p1); p2 = wred_sum(p2); p3 = wred_sum(p3);
      if (lane == 0) {
        const int m = c * CHUNK + mm;
        lw[wid * 4 + 0][m] = p0; lw[wid * 4 + 1][m] = p1;
        lw[wid * 4 + 2][m] = p2; lw[wid * 4 + 3][m] = p3;
      }
    }
  }
  __syncthreads();

  // ---- phase 2: cosine scale -> softmax -> shrink -> L1 normalize ----
  const float t = 0.005f;  // 1/MEM
#pragma unroll
  for (int r = 0; r < 4; ++r) {
    const int lr = wid * 4 + r;
    float lg[4];
#pragma unroll
    for (int i = 0; i < 4; ++i) {
      const int m = lane + 64 * i;
      lg[i] = (m < MEM_DIM) ? lw[lr][m] / fmaxf(zn[r] * mnsh[m], 1e-8f) : -1e30f;
    }
    float mx = wred_max(fmaxf(fmaxf(lg[0], lg[1]), fmaxf(lg[2], lg[3])));
    float e[4]; float s = 0.f;
#pragma unroll
    for (int i = 0; i < 4; ++i) {
      const int m = lane + 64 * i;
      e[i] = (m < MEM_DIM) ? expf(lg[i] - mx) : 0.f;
      s += e[i];
    }
    s = wred_sum(s);
    float sv[4]; float l1 = 0.f;
#pragma unroll
    for (int i = 0; i < 4; ++i) {
      const float wv = e[i] / s;
      const float d = wv - t;
      sv[i] = fmaxf(d, 0.f) * wv / (fabsf(d) + 1e-12f);
      l1 += sv[i];
    }
    l1 = wred_sum(l1);
    const float dnm = fmaxf(l1, 1e-12f);
#pragma unroll
    for (int i = 0; i < 4; ++i) {
      const int m = lane + 64 * i;
      if (m < MEM_DIM) {
        const float wn = sv[i] / dnm;
        lw[lr][m] = wn;
        w_out[(size_t)(row0 + lr) * MEM_DIM + m] = wn;
      }
    }
  }

  // ---- phase 3: z_hat = w @ mem ----
  f32x4 acc[4] = {};
  for (int c = 0; c < 5; ++c) {
    __syncthreads();
    const float4* gsrc = (const float4*)(mem + (size_t)c * CHUNK * LAT);
    float4* msh4 = (float4*)msh;
    for (int i = tid; i < CHUNK * 64; i += 256) msh4[i] = gsrc[i];
    __syncthreads();
    for (int mm = 0; mm < CHUNK; ++mm) {
      float4 mv = ((float4*)msh)[mm * 64 + lane];
      const int m = c * CHUNK + mm;
#pragma unroll
      for (int r = 0; r < 4; ++r) {
        const float wm = lw[wid * 4 + r][m];
        acc[r][0] += wm * mv.x; acc[r][1] += wm * mv.y;
        acc[r][2] += wm * mv.z; acc[r][3] += wm * mv.w;
      }
    }
  }
#pragma unroll
  for (int r = 0; r < 4; ++r) {
    const int row = row0 + wid * 4 + r;
    float4 o; o.x = acc[r][0]; o.y = acc[r][1]; o.z = acc[r][2]; o.w = acc[r][3];
    *(float4*)(zhat_out + (size_t)row * LAT + lane * 4) = o;
    ushort4 ob; ob.x = f2bf(o.x); ob.y = f2bf(o.y); ob.z = f2bf(o.z); ob.w = f2bf(o.w);
    *(ushort4*)(zhat_bf + (size_t)row * LAT + lane * 4) = ob;
  }
}

// ---------------- x_hat = zhat_bf @ Wb^T + bias  (UNCHANGED from round 3) ----------------
__global__ void __launch_bounds__(256, 3) gemm_xhat_kernel(
    const unsigned short* __restrict__ A,    // zhat bf16 [B_DIM][LAT]
    const unsigned short* __restrict__ Bw,   // W bf16 [NPIX][LAT]
    const float* __restrict__ bias,          // [NPIX]
    float* __restrict__ C) {                 // [B_DIM][NPIX]
  __shared__ unsigned short Ash[2][128 * 32];   // 2 x 8 KB
  __shared__ unsigned short Bsh[2][128 * 32];   // 2 x 8 KB

  const int tid = threadIdx.x;
  const int lane = tid & 63;
  const int wid = tid >> 6;

  const int swz = (blockIdx.x & 7) * 1024 + (blockIdx.x >> 3);
  const int st = swz >> 8;
  const int loc = swz & 255;
  const int tm = (st >> 3) * 16 + (loc & 15);
  const int tn = (st & 7) * 16 + (loc >> 4);
  const int brow = tm * 128;
  const int bcol = tn * 128;

  const int wr = wid >> 1, wc = wid & 1;

  const int ch0 = wid * 2;
  const int r0 = ch0 * 16 + (lane >> 2);
  const int kq = (lane & 3) * 8;

  f32x4 acc[4][4] = {};

#define STAGE(buf, t)                                                          \
  {                                                                            \
    const int k0_ = (t) * 32;                                                  \
    _Pragma("unroll")                                                          \
    for (int cc = 0; cc < 2; ++cc) {                                           \
      const int r_ = r0 + cc * 16;                                             \
      __builtin_amdgcn_global_load_lds(                                        \
          (const __attribute__((address_space(1))) void*)(const void*)         \
              (A + (size_t)(brow + r_) * LAT + k0_ + kq),                      \
          (__attribute__((address_space(3))) void*)(void*)                     \
              &Ash[buf][(ch0 + cc) * 512], 16, 0, 0);                          \
      __builtin_amdgcn_global_load_lds(                                        \
          (const __attribute__((address_space(1))) void*)(const void*)         \
              (Bw + (size_t)(bcol + r_) * LAT + k0_ + kq),                     \
          (__attribute__((address_space(3))) void*)(void*)                     \
              &Bsh[buf][(ch0 + cc) * 512], 16, 0, 0);                          \
    }                                                                          \
  }

  STAGE(0, 0);
  __syncthreads();

#pragma unroll
  for (int t = 0; t < 8; ++t) {
    const int cur = t & 1;
    if (t < 7) STAGE(cur ^ 1, t + 1);

    bf16x8 af[4], bfr[4];
#pragma unroll
    for (int mf = 0; mf < 4; ++mf)
      af[mf] = *(const bf16x8*)&Ash[cur][(wr * 64 + mf * 16 + (lane & 15)) * 32 + ((lane >> 4) * 8)];
#pragma unroll
    for (int nf = 0; nf < 4; ++nf)
      bfr[nf] = *(const bf16x8*)&Bsh[cur][(wc * 64 + nf * 16 + (lane & 15)) * 32 + ((lane >> 4) * 8)];
#pragma unroll
    for (int mf = 0; mf < 4; ++mf)
#pragma unroll
      for (int nf = 0; nf < 4; ++nf)
        acc[mf][nf] = __builtin_amdgcn_mfma_f32_16x16x32_bf16(af[mf], bfr[nf], acc[mf][nf], 0, 0, 0);

    if (t < 7) __syncthreads();
  }
#undef STAGE

#pragma unroll
  for (int nf = 0; nf < 4; ++nf) {
    const int col = bcol + wc * 64 + nf * 16 + (lane & 15);
    const float bv = bias[col];
#pragma unroll
    for (int mf = 0; mf < 4; ++mf) {
      const int row = brow + wr * 64 + mf * 16 + ((lane >> 4) << 2);
#pragma unroll
      for (int q = 0; q < 4; ++q)
        C[(size_t)(row + q) * NPIX + col] = acc[mf][nf][q] + bv;
    }
  }
}

extern "C" void kernel_launch(void* const* d_in, const int* in_sizes, int n_in,
                              void* d_out, int out_size, void* d_ws, size_t ws_size,
                              hipStream_t stream) {
  const float* z    = (const float*)d_in[0];
  const float* mem  = (const float*)d_in[1];
  const float* W    = (const float*)d_in[2];
  const float* bias = (const float*)d_in[3];

  float* xhat = (float*)d_out;                       // [B_DIM][NPIX]
  float* zhat = xhat + (size_t)B_DIM * NPIX;         // [B_DIM][LAT]
  float* wout = zhat + (size_t)B_DIM * LAT;          // [B_DIM][MEM_DIM]

  unsigned short* Wb  = (unsigned short*)d_ws;
  unsigned short* zhb = Wb + (size_t)NPIX * LAT;
  float* mn = (float*)(zhb + (size_t)B_DIM * LAT);

  mem_norm_kernel<<<MEM_DIM, 64, 0, stream>>>(mem, mn);
  convert_w_kernel<<<(NPIX * LAT / 4) / 256, 256, 0, stream>>>(W, Wb);
  row_kernel<<<B_DIM / RPB, 256, 0, stream>>>(z, mem, mn, zhat, wout, zhb);
  // INSTRUMENTATION ROUND: launch the identical GEMM 4x (idempotent stores, so
  // output is unchanged). gemm_cost(warm) = (dur_us_total - 384)/3. This decides
  // whether the missing ~150us lives in the GEMM (-> port 8-phase template) or
  // in the front-end/launch path (-> fuse front-end kernels).
  gemm_xhat_kernel<<<8192, 256, 0, stream>>>(zhb, Wb, bias, xhat);
  gemm_xhat_kernel<<<8192, 256, 0, stream>>>(zhb, Wb, bias, xhat);
  gemm_xhat_kernel<<<8192, 256, 0, stream>>>(zhb, Wb, bias, xhat);
  gemm_xhat_kernel<<<8192, 256, 0, stream>>>(zhb, Wb, bias, xhat);
}

// Round 5
// 315.200 us; speedup vs baseline: 3.5731x; 3.5731x over previous
//
#include <hip/hip_runtime.h>
#include <hip/hip_bf16.h>
#include <stdint.h>

// Problem dims (fixed by the reference)
#define B_DIM   8192
#define LAT     256
#define MEM_DIM 200
#define NPIX    16384          // IMG*IMG = 128*128
#define RPB     16             // batch rows per block in row_kernel (round-1 proven)
#define CHUNK   40             // memory rows per LDS chunk (5 chunks x 40 = 200)

typedef short bf16x8 __attribute__((ext_vector_type(8)));
typedef float f32x4  __attribute__((ext_vector_type(4)));

__device__ __forceinline__ float wred_sum(float v) {
#pragma unroll
  for (int m = 32; m; m >>= 1) v += __shfl_xor(v, m, 64);
  return v;
}
__device__ __forceinline__ float wred_max(float v) {
#pragma unroll
  for (int m = 32; m; m >>= 1) v = fmaxf(v, __shfl_xor(v, m, 64));
  return v;
}
// round-to-nearest-even fp32 -> bf16 (bit trick; inputs are normal floats)
__device__ __forceinline__ unsigned short f2bf(float f) {
  unsigned u = __builtin_bit_cast(unsigned, f);
  u = u + 0x7FFFu + ((u >> 16) & 1u);
  return (unsigned short)(u >> 16);
}

// ---------------- memory row norms: mn[m] = ||memory[m,:]|| ----------------
__global__ void __launch_bounds__(64) mem_norm_kernel(const float* __restrict__ mem,
                                                      float* __restrict__ mn) {
  const int m = blockIdx.x, lane = threadIdx.x;
  float4 v = ((const float4*)(mem + (size_t)m * LAT))[lane];
  float ss = v.x * v.x + v.y * v.y + v.z * v.z + v.w * v.w;
  ss = wred_sum(ss);
  if (lane == 0) mn[m] = sqrtf(ss);
}

// ---------------- W fp32 -> bf16 (row-major [NPIX][LAT]) ----------------
__global__ void __launch_bounds__(256) convert_w_kernel(const float* __restrict__ W,
                                                        unsigned short* __restrict__ Wb) {
  const int i = blockIdx.x * 256 + threadIdx.x;   // quad index, grid covers exactly NPIX*LAT/4
  float4 v = ((const float4*)W)[i];
  ushort4 o;
  o.x = f2bf(v.x); o.y = f2bf(v.y); o.z = f2bf(v.z); o.w = f2bf(v.w);
  ((ushort4*)Wb)[i] = o;
}

// ---------------- fused per-row pipeline (round-1 version, measured-good) ----------------
__global__ void __launch_bounds__(256) row_kernel(
    const float* __restrict__ z, const float* __restrict__ mem,
    const float* __restrict__ mn_g, float* __restrict__ zhat_out,
    float* __restrict__ w_out, unsigned short* __restrict__ zhat_bf) {
  __shared__ float msh[CHUNK * LAT];     // 40 KB
  __shared__ float lw[RPB][MEM_DIM];     // 12.8 KB: raw dots, then final w
  __shared__ float mnsh[MEM_DIM];

  const int tid = threadIdx.x;
  const int lane = tid & 63;
  const int wid = tid >> 6;
  const int row0 = blockIdx.x * RPB;

  if (tid < MEM_DIM) mnsh[tid] = mn_g[tid];

  float4 zr[4];
  float zn[4];
#pragma unroll
  for (int r = 0; r < 4; ++r) {
    const int row = row0 + wid * 4 + r;
    zr[r] = *(const float4*)(z + (size_t)row * LAT + lane * 4);
    float ss = zr[r].x * zr[r].x + zr[r].y * zr[r].y + zr[r].z * zr[r].z + zr[r].w * zr[r].w;
    zn[r] = sqrtf(wred_sum(ss));
  }

  // ---- phase 1: raw dot products  lw[r][m] = z_r . mem[m] ----
  for (int c = 0; c < 5; ++c) {
    __syncthreads();
    const float4* gsrc = (const float4*)(mem + (size_t)c * CHUNK * LAT);
    float4* msh4 = (float4*)msh;
    for (int i = tid; i < CHUNK * 64; i += 256) msh4[i] = gsrc[i];
    __syncthreads();
    for (int mm = 0; mm < CHUNK; ++mm) {
      float4 mv = ((float4*)msh)[mm * 64 + lane];
      float p0 = mv.x * zr[0].x + mv.y * zr[0].y + mv.z * zr[0].z + mv.w * zr[0].w;
      float p1 = mv.x * zr[1].x + mv.y * zr[1].y + mv.z * zr[1].z + mv.w * zr[1].w;
      float p2 = mv.x * zr[2].x + mv.y * zr[2].y + mv.z * zr[2].z + mv.w * zr[2].w;
      float p3 = mv.x * zr[3].x + mv.y * zr[3].y + mv.z * zr[3].z + mv.w * zr[3].w;
      p0 = wred_sum(p0); p1 = wred_sum(p1); p2 = wred_sum(p2); p3 = wred_sum(p3);
      if (lane == 0) {
        const int m = c * CHUNK + mm;
        lw[wid * 4 + 0][m] = p0; lw[wid * 4 + 1][m] = p1;
        lw[wid * 4 + 2][m] = p2; lw[wid * 4 + 3][m] = p3;
      }
    }
  }
  __syncthreads();

  // ---- phase 2: cosine scale -> softmax -> shrink -> L1 normalize ----
  const float t = 0.005f;  // 1/MEM
#pragma unroll
  for (int r = 0; r < 4; ++r) {
    const int lr = wid * 4 + r;
    float lg[4];
#pragma unroll
    for (int i = 0; i < 4; ++i) {
      const int m = lane + 64 * i;
      lg[i] = (m < MEM_DIM) ? lw[lr][m] / fmaxf(zn[r] * mnsh[m], 1e-8f) : -1e30f;
    }
    float mx = wred_max(fmaxf(fmaxf(lg[0], lg[1]), fmaxf(lg[2], lg[3])));
    float e[4]; float s = 0.f;
#pragma unroll
    for (int i = 0; i < 4; ++i) {
      const int m = lane + 64 * i;
      e[i] = (m < MEM_DIM) ? expf(lg[i] - mx) : 0.f;
      s += e[i];
    }
    s = wred_sum(s);
    float sv[4]; float l1 = 0.f;
#pragma unroll
    for (int i = 0; i < 4; ++i) {
      const float wv = e[i] / s;
      const float d = wv - t;
      sv[i] = fmaxf(d, 0.f) * wv / (fabsf(d) + 1e-12f);
      l1 += sv[i];
    }
    l1 = wred_sum(l1);
    const float dnm = fmaxf(l1, 1e-12f);
#pragma unroll
    for (int i = 0; i < 4; ++i) {
      const int m = lane + 64 * i;
      if (m < MEM_DIM) {
        const float wn = sv[i] / dnm;
        lw[lr][m] = wn;
        w_out[(size_t)(row0 + lr) * MEM_DIM + m] = wn;
      }
    }
  }

  // ---- phase 3: z_hat = w @ mem ----
  f32x4 acc[4] = {};
  for (int c = 0; c < 5; ++c) {
    __syncthreads();
    const float4* gsrc = (const float4*)(mem + (size_t)c * CHUNK * LAT);
    float4* msh4 = (float4*)msh;
    for (int i = tid; i < CHUNK * 64; i += 256) msh4[i] = gsrc[i];
    __syncthreads();
    for (int mm = 0; mm < CHUNK; ++mm) {
      float4 mv = ((float4*)msh)[mm * 64 + lane];
      const int m = c * CHUNK + mm;
#pragma unroll
      for (int r = 0; r < 4; ++r) {
        const float wm = lw[wid * 4 + r][m];
        acc[r][0] += wm * mv.x; acc[r][1] += wm * mv.y;
        acc[r][2] += wm * mv.z; acc[r][3] += wm * mv.w;
      }
    }
  }
#pragma unroll
  for (int r = 0; r < 4; ++r) {
    const int row = row0 + wid * 4 + r;
    float4 o; o.x = acc[r][0]; o.y = acc[r][1]; o.z = acc[r][2]; o.w = acc[r][3];
    *(float4*)(zhat_out + (size_t)row * LAT + lane * 4) = o;
    ushort4 ob; ob.x = f2bf(o.x); ob.y = f2bf(o.y); ob.z = f2bf(o.z); ob.w = f2bf(o.w);
    *(ushort4*)(zhat_bf + (size_t)row * LAT + lane * 4) = ob;
  }
}

// ---------------- x_hat = zhat_bf @ Wb^T + bias  (bf16 MFMA, 2-phase dbuf) ----------------
// Round-5 change: LDS-TRANSPOSE EPILOGUE. The old epilogue stored 64-B segments
// (16 lanes x 4 B), so every 128-B C line was first touched by a partial write
// (suspected write-allocate RMW fetch: ~537 MB extra HBM reads -> GEMM 247 us at
// 2.2 TB/s effective). Now each wave round-trips acc through a per-wave LDS tile
// and stores full rows: 16 lanes x dwordx4 = 256-B aligned contiguous segments
// -> only full 128-B lines written. Same values, bitwise-identical output.
#define TSTRIDE 68   // fp32 row stride of transpose tile: 16-B aligned, 2-way-conflict-free
__global__ void __launch_bounds__(256, 3) gemm_xhat_kernel(
    const unsigned short* __restrict__ A,    // zhat bf16 [B_DIM][LAT]
    const unsigned short* __restrict__ Bw,   // W bf16 [NPIX][LAT]
    const float* __restrict__ bias,          // [NPIX]
    float* __restrict__ C) {                 // [B_DIM][NPIX]
  // 32 KB shared, overlaid: K-loop uses Ash/Bsh; epilogue reuses it per-wave.
  __shared__ __align__(16) unsigned char smem[32768];
  unsigned short* Ash0 = (unsigned short*)smem;            // [2][128*32]
  unsigned short* Bsh0 = (unsigned short*)(smem + 16384);  // [2][128*32]

  const int tid = threadIdx.x;
  const int lane = tid & 63;
  const int wid = tid >> 6;

  const int swz = (blockIdx.x & 7) * 1024 + (blockIdx.x >> 3);
  const int st = swz >> 8;
  const int loc = swz & 255;
  const int tm = (st >> 3) * 16 + (loc & 15);
  const int tn = (st & 7) * 16 + (loc >> 4);
  const int brow = tm * 128;
  const int bcol = tn * 128;

  const int wr = wid >> 1, wc = wid & 1;

  const int ch0 = wid * 2;
  const int r0 = ch0 * 16 + (lane >> 2);
  const int kq = (lane & 3) * 8;

  f32x4 acc[4][4] = {};

#define STAGE(buf, t)                                                          \
  {                                                                            \
    const int k0_ = (t) * 32;                                                  \
    _Pragma("unroll")                                                          \
    for (int cc = 0; cc < 2; ++cc) {                                           \
      const int r_ = r0 + cc * 16;                                             \
      __builtin_amdgcn_global_load_lds(                                        \
          (const __attribute__((address_space(1))) void*)(const void*)         \
              (A + (size_t)(brow + r_) * LAT + k0_ + kq),                      \
          (__attribute__((address_space(3))) void*)(void*)                     \
              &Ash0[(buf) * 4096 + (ch0 + cc) * 512], 16, 0, 0);               \
      __builtin_amdgcn_global_load_lds(                                        \
          (const __attribute__((address_space(1))) void*)(const void*)         \
              (Bw + (size_t)(bcol + r_) * LAT + k0_ + kq),                     \
          (__attribute__((address_space(3))) void*)(void*)                     \
              &Bsh0[(buf) * 4096 + (ch0 + cc) * 512], 16, 0, 0);               \
    }                                                                          \
  }

  STAGE(0, 0);
  __syncthreads();

#pragma unroll
  for (int t = 0; t < 8; ++t) {
    const int cur = t & 1;
    if (t < 7) STAGE(cur ^ 1, t + 1);

    bf16x8 af[4], bfr[4];
#pragma unroll
    for (int mf = 0; mf < 4; ++mf)
      af[mf] = *(const bf16x8*)&Ash0[cur * 4096 + (wr * 64 + mf * 16 + (lane & 15)) * 32 + ((lane >> 4) * 8)];
#pragma unroll
    for (int nf = 0; nf < 4; ++nf)
      bfr[nf] = *(const bf16x8*)&Bsh0[cur * 4096 + (wc * 64 + nf * 16 + (lane & 15)) * 32 + ((lane >> 4) * 8)];
#pragma unroll
    for (int mf = 0; mf < 4; ++mf)
#pragma unroll
      for (int nf = 0; nf < 4; ++nf)
        acc[mf][nf] = __builtin_amdgcn_mfma_f32_16x16x32_bf16(af[mf], bfr[nf], acc[mf][nf], 0, 0, 0);

    if (t < 7) __syncthreads();
  }
#undef STAGE

  // ---- epilogue: per-wave LDS transpose -> full-line dwordx4 stores ----
  __syncthreads();   // all waves done with Ash/Bsh before overlay reuse
  float* tt = (float*)(smem + wid * (16 * TSTRIDE * 4));   // per-wave [16][TSTRIDE] fp32

  // this lane's output columns (4 consecutive): same for all mf/rr
  const int colq = (lane & 15) * 4;                        // 0..60 within 64-col span
  const int col0 = bcol + wc * 64 + colq;
  const float4 bv4 = *(const float4*)(bias + col0);

#pragma unroll
  for (int mf = 0; mf < 4; ++mf) {
    // scatter acc[mf][*] into LDS: row_local = (lane>>4)*4+q, col_local = nf*16+(lane&15)
#pragma unroll
    for (int nf = 0; nf < 4; ++nf) {
      const int cl = nf * 16 + (lane & 15);
#pragma unroll
      for (int q = 0; q < 4; ++q)
        tt[((lane >> 4) * 4 + q) * TSTRIDE + cl] = acc[mf][nf][q];
    }
    // gather rows: lane reads row rr*4+(lane>>4), cols colq..colq+3 (b128)
#pragma unroll
    for (int rr = 0; rr < 4; ++rr) {
      const int rl = rr * 4 + (lane >> 4);
      float4 v = *(const float4*)&tt[rl * TSTRIDE + colq];
      v.x += bv4.x; v.y += bv4.y; v.z += bv4.z; v.w += bv4.w;
      const int row = brow + wr * 64 + mf * 16 + rl;
      *(float4*)&C[(size_t)row * NPIX + col0] = v;
    }
    // per-wave region, same-wave write->read->overwrite; compiler inserts
    // lgkmcnt waits for the RAW/WAR chains (no cross-wave sharing).
  }
}

extern "C" void kernel_launch(void* const* d_in, const int* in_sizes, int n_in,
                              void* d_out, int out_size, void* d_ws, size_t ws_size,
                              hipStream_t stream) {
  const float* z    = (const float*)d_in[0];
  const float* mem  = (const float*)d_in[1];
  const float* W    = (const float*)d_in[2];
  const float* bias = (const float*)d_in[3];

  float* xhat = (float*)d_out;                       // [B_DIM][NPIX]
  float* zhat = xhat + (size_t)B_DIM * NPIX;         // [B_DIM][LAT]
  float* wout = zhat + (size_t)B_DIM * LAT;          // [B_DIM][MEM_DIM]

  unsigned short* Wb  = (unsigned short*)d_ws;
  unsigned short* zhb = Wb + (size_t)NPIX * LAT;
  float* mn = (float*)(zhb + (size_t)B_DIM * LAT);

  mem_norm_kernel<<<MEM_DIM, 64, 0, stream>>>(mem, mn);
  convert_w_kernel<<<(NPIX * LAT / 4) / 256, 256, 0, stream>>>(W, Wb);
  row_kernel<<<B_DIM / RPB, 256, 0, stream>>>(z, mem, mn, zhat, wout, zhb);
  gemm_xhat_kernel<<<8192, 256, 0, stream>>>(zhb, Wb, bias, xhat);
}